// Round 6
// baseline (1540.900 us; speedup 1.0000x reference)
//
#include <hip/hip_runtime.h>
#include <math.h>

#define TT 250
#define BT 256
#define HN 128
#define ON 20
#define KIN 700
#define NKT 22

// ws layout (float offsets): xin[250*256*128] | packed W hi | packed W lo
#define XIN_OFF 0
#define WPKH_OFF 8192000   // 45056 floats (90112 bf16)
#define WPKL_OFF 8237056   // 45056 floats

typedef __attribute__((ext_vector_type(8))) short bf16x8;
typedef __attribute__((ext_vector_type(4))) float f32x4;

__device__ __forceinline__ unsigned short bf16rne(float f) {
    unsigned u = __float_as_uint(f);
    unsigned r = u + 0x7fffu + ((u >> 16) & 1u);
    return (unsigned short)(r >> 16);
}
__device__ __forceinline__ void hilo(float v, short& h, short& l) {
    unsigned short hh = bf16rne(v);
    float vh = __uint_as_float((unsigned)hh << 16);
    h = (short)hh;
    l = (short)bf16rne(v - vh);
}

// ---------------------------------------------------------------------------
// pack w_ih1 (700x128, zero-pad K to 704) into MFMA B-frag order, hi/lo bf16.
// ---------------------------------------------------------------------------
__global__ __launch_bounds__(256) void packw(const float* __restrict__ w,
                                             unsigned short* __restrict__ ph,
                                             unsigned short* __restrict__ pl) {
    int i = blockIdx.x * 256 + threadIdx.x;   // 352*256 = 90112 = 704*128
    int k = i >> 7, c = i & 127;
    float v = (k < KIN) ? w[k * HN + c] : 0.f;
    short h, l;
    hilo(v, h, l);
    int dst = (((k >> 5) * 8 + (c >> 4)) * 64 + (((k >> 3) & 3) * 16 + (c & 15))) * 8 + (k & 7);
    ph[dst] = (unsigned short)h;
    pl[dst] = (unsigned short)l;
}

// ---------------------------------------------------------------------------
// input projection via MFMA. B staged in LDS (double-buffered); A (x rows)
// register double-buffered so the global-load latency is covered by a full
// MFMA segment instead of being consumed immediately.
// ---------------------------------------------------------------------------
__global__ __launch_bounds__(256) void gemm_in(const float* __restrict__ x,
        const bf16x8* __restrict__ wph, const bf16x8* __restrict__ wpl,
        const float* __restrict__ bias1, const float* __restrict__ bias2,
        float* __restrict__ xin) {
    __shared__ __align__(16) short Bs[2][2][4096];   // [buf][hi/lo][8KB]
    const int tid = threadIdx.x;
    const int w = tid >> 6, lane = tid & 63;
    const int q = lane >> 4, li = lane & 15;
    const long mrow = (long)blockIdx.x * 64 + w * 16 + li;
    const float* xr = x + mrow * KIN + q * 8;

    float b12[8];
#pragma unroll
    for (int nt = 0; nt < 8; nt++) b12[nt] = bias1[nt * 16 + li] + bias2[nt * 16 + li];

    f32x4 acc[8];
#pragma unroll
    for (int nt = 0; nt < 8; nt++) acc[nt] = (f32x4){0.f, 0.f, 0.f, 0.f};

    {   // prestage B kt=0
        bf16x8* dh = (bf16x8*)Bs[0][0];
        bf16x8* dl = (bf16x8*)Bs[0][1];
        dh[tid] = wph[tid]; dh[tid + 256] = wph[tid + 256];
        dl[tid] = wpl[tid]; dl[tid + 256] = wpl[tid + 256];
    }
    // preload A kt=0
    float avC[8];
    *(float4*)&avC[0] = *(const float4*)xr;
    *(float4*)&avC[4] = *(const float4*)(xr + 4);
    __syncthreads();

    for (int kt = 0; kt < NKT; kt++) {
        const int cur = kt & 1;
        const bool more = (kt + 1 < NKT);
        bf16x8 nh0, nh1, nl0, nl1;
        float avN[8];
        if (more) {
            const int base = (kt + 1) * 512 + tid;
            nh0 = wph[base]; nh1 = wph[base + 256];
            nl0 = wpl[base]; nl1 = wpl[base + 256];
            const float* p = xr + (kt + 1) * 32;
            *(float4*)&avN[0] = *(const float4*)p;
            if (kt + 1 == NKT - 1 && q == 3) { avN[4] = 0.f; avN[5] = 0.f; avN[6] = 0.f; avN[7] = 0.f; }
            else *(float4*)&avN[4] = *(const float4*)(p + 4);
        }
        bf16x8 ah, al;
#pragma unroll
        for (int j = 0; j < 8; j++) { short h, l; hilo(avC[j], h, l); ah[j] = h; al[j] = l; }

        const bf16x8* bh = (const bf16x8*)Bs[cur][0];
        const bf16x8* bl = (const bf16x8*)Bs[cur][1];
#pragma unroll
        for (int nt = 0; nt < 8; nt++) {
            bf16x8 vh = bh[nt * 64 + lane];
            bf16x8 vl = bl[nt * 64 + lane];
            acc[nt] = __builtin_amdgcn_mfma_f32_16x16x32_bf16(ah, vh, acc[nt], 0, 0, 0);
            acc[nt] = __builtin_amdgcn_mfma_f32_16x16x32_bf16(al, vh, acc[nt], 0, 0, 0);
            acc[nt] = __builtin_amdgcn_mfma_f32_16x16x32_bf16(ah, vl, acc[nt], 0, 0, 0);
        }
        if (more) {
            bf16x8* dh = (bf16x8*)Bs[cur ^ 1][0];
            bf16x8* dl = (bf16x8*)Bs[cur ^ 1][1];
            dh[tid] = nh0; dh[tid + 256] = nh1;
            dl[tid] = nl0; dl[tid + 256] = nl1;
#pragma unroll
            for (int j = 0; j < 8; j++) avC[j] = avN[j];
        }
        __syncthreads();
    }

#pragma unroll
    for (int r = 0; r < 4; r++) {
        int m = blockIdx.x * 64 + w * 16 + q * 4 + r;
        int bq = (int)(((unsigned long long)m * 67109ull) >> 24);  // m/250
        int tt = m - bq * 250;
        float* dst = xin + ((size_t)tt * BT + bq) * HN;
#pragma unroll
        for (int nt = 0; nt < 8; nt++) dst[nt * 16 + li] = acc[nt][r] + b12[nt];
    }
}

// ---------------------------------------------------------------------------
// scan v8: 16 blocks x 512 thr (8 waves, 2/SIMD), wave w owns cols w*16..+15,
// full hi+lo weights per wave (v5-proven register budget). ONE barrier/step:
// after barrier i, MFMAs use published S1(i), S2(i-1): W11*S1(i) [->i1(i+1)],
// W12*S1(i) + W22*S2(i-1) [->i2(i)], WHO*S2(i-1) [->om(i-1), consumed next
// iter]. VALU then does update-2(i) -> S2(i), update-1(i+1) -> S1(i+1) into
// the opposite frag buffer. WHO split 2 MFMA/wave (8 tasks: nt x hi/lo x
// ktpair), partials via double-buffered LDS, om lags 2 steps (3-stage tail).
// ---------------------------------------------------------------------------
__global__ __launch_bounds__(512, 2) void snn_scan(
    const float* __restrict__ xin, const float* __restrict__ mask,
    const float* __restrict__ w_h1h1, const float* __restrict__ w_h1h2,
    const float* __restrict__ b_h1h2, const float* __restrict__ w_h2h2,
    const float* __restrict__ b_h2h2, const float* __restrict__ w_h2o,
    const float* __restrict__ b_h2o, const float* __restrict__ tau_adp1,
    const float* __restrict__ tau_adp2, const float* __restrict__ taum1,
    const float* __restrict__ taum2, const float* __restrict__ taumo,
    const float* __restrict__ h1m0, const float* __restrict__ h2m0,
    const float* __restrict__ om0, float* __restrict__ out) {

    __shared__ __align__(16) unsigned short sF1[2][2048];
    __shared__ __align__(16) unsigned short sF2[2][2048];
    __shared__ float Opart[2][8][16][16];
    __shared__ float red[8];

    const int tid = threadIdx.x;
    const int w = tid >> 6, lane = tid & 63;
    const int q = lane >> 4, li = lane & 15;
    const int col = w * 16 + li;
    const int r0 = blockIdx.x * 16;

    // ---- weights (register-resident, full hi+lo per wave) ----
    bf16x8 f11h[4], f11l[4], f12h[4], f12l[4], f22h[4], f22l[4], fO[2];
    const int ont = w & 1, ohalf = (w >> 1) & 1, okp = w >> 2;
    const int ocol = ont * 16 + li;
    const bool oval = ocol < ON;
    float pn = 0.f;
#pragma unroll
    for (int kt = 0; kt < 4; kt++) {
#pragma unroll
        for (int j = 0; j < 8; j++) {
            const int k = kt * 32 + q * 8 + j;
            const int idx = k * HN + col;
            float v11 = w_h1h1[idx] * mask[idx];
            float v22 = w_h2h2[idx] * mask[HN * HN + idx];
            float v12 = w_h1h2[idx];
            pn += fabsf(v11) + fabsf(v22);
            short h, l;
            hilo(v11, h, l); f11h[kt][j] = h; f11l[kt][j] = l;
            hilo(v22, h, l); f22h[kt][j] = h; f22l[kt][j] = l;
            hilo(v12, h, l); f12h[kt][j] = h; f12l[kt][j] = l;
        }
    }
#pragma unroll
    for (int kk = 0; kk < 2; kk++) {
#pragma unroll
        for (int j = 0; j < 8; j++) {
            const int k = (okp * 2 + kk) * 32 + q * 8 + j;
            float vO = oval ? w_h2o[k * ON + ocol] : 0.f;
            short h, l;
            hilo(vO, h, l);
            fO[kk][j] = ohalf ? l : h;
        }
    }

    // ---- per-lane constants & state (4 rows x 1 col) ----
    const float a1 = expf(-1.f / taum1[col]);
    const float r1c = expf(-1.f / tau_adp1[col]);
    const float a2 = expf(-1.f / taum2[col]);
    const float r2c = expf(-1.f / tau_adp2[col]);
    const float oma1 = 1.f - a1, omr1 = 1.f - r1c;
    const float oma2 = 1.f - a2, omr2 = 1.f - r2c;
    const float cc2 = b_h1h2[col] + b_h2h2[col];
    float h1m[4], h2m[4], b1a[4], b2a[4], c1[4], c2n[4];
    unsigned s1bits = 0, s2bits = 0;
#pragma unroll
    for (int r = 0; r < 4; r++) {
        h1m[r] = h1m0[(r0 + q * 4 + r) * HN + col];
        h2m[r] = h2m0[(r0 + q * 4 + r) * HN + col];
        b1a[r] = 0.01f; b2a[r] = 0.01f; c1[r] = 0.f; c2n[r] = 0.f;
    }
    // wave-7 om/softmax state: lane -> row sm, outputs ob..ob+4
    const int sm = lane >> 2, ob = (lane & 3) * 5;
    float om[5], accs[5], aoc[5], bjoc[5];
    if (w == 7) {
#pragma unroll
        for (int i = 0; i < 5; i++) {
            aoc[i] = expf(-1.f / taumo[ob + i]);
            bjoc[i] = b_h2o[ob + i];
            om[i] = om0[(r0 + sm) * ON + ob + i];
            accs[i] = 0.f;
        }
    }

    // zero S2 buffer 0 (S2(-1) = 0)
    ((unsigned*)sF2[0])[tid] = 0u;
    ((unsigned*)sF2[0])[tid + 512] = 0u;

    // A_norm
#pragma unroll
    for (int off = 32; off > 0; off >>= 1) pn += __shfl_down(pn, off);
    if (lane == 0) red[w] = pn;

    // frag write offset: elem (row m=q*4+r, col) -> kt=(w>>1), q8, j
    const int wbase = (w >> 1) * 512 + (((2 * w + (li >> 3)) & 3) * 128) + q * 32 + (li & 7);
    const unsigned short ONE = 0x3F80u;

    // ---- prologue: S1(0) from i1(0) = xin(0) (biases folded; W11*0 = 0) ----
    {
        float xt0[4];
#pragma unroll
        for (int r = 0; r < 4; r++)
            xt0[r] = xin[(size_t)(r0 + q * 4 + r) * HN + col];
#pragma unroll
        for (int r = 0; r < 4; r++) {
            b1a[r] = r1c * b1a[r];                    // sv = 0
            const float B = fmaf(1.8f, b1a[r], 0.01f);
            h1m[r] = fmaf(a1, h1m[r], oma1 * xt0[r]);
            const bool sp = h1m[r] > B;
            s1bits |= (sp ? 1u : 0u) << r;
            c1[r] += sp ? 1.f : 0.f;
            sF1[0][wbase + r * 8] = sp ? ONE : (unsigned short)0;
        }
    }
    __syncthreads();
    if (tid == 0 && blockIdx.x == 0) {
        float s = 0.f;
#pragma unroll
        for (int i = 0; i < 8; i++) s += red[i];
        out[70656] = s;
    }

    const float* px = xin + (size_t)BT * HN + (size_t)(r0 + q * 4) * HN + col;

    for (int i = 0; i < TT - 1; i++) {
        const int rb = i & 1;      // read frag buf; Opart write buf
        const int wb = rb ^ 1;     // write frag buf; Opart read buf
        const bf16x8* s1 = (const bf16x8*)sF1[rb];
        const bf16x8* s2 = (const bf16x8*)sF2[rb];
        bf16x8 g1[4], g2[4];
#pragma unroll
        for (int kt = 0; kt < 4; kt++) {
            g1[kt] = s1[kt * 64 + lane];
            g2[kt] = s2[kt * 64 + lane];
        }
        // xin(i+1) prefetch (consumed after the MFMA segment)
        float xt[4];
#pragma unroll
        for (int r = 0; r < 4; r++) xt[r] = px[r * HN];
        px += (size_t)BT * HN;

        f32x4 aA = {0.f, 0.f, 0.f, 0.f}, aB = {0.f, 0.f, 0.f, 0.f};
        f32x4 aC = {0.f, 0.f, 0.f, 0.f}, aO = {0.f, 0.f, 0.f, 0.f};
#pragma unroll
        for (int kt = 0; kt < 4; kt++) {
            aA = __builtin_amdgcn_mfma_f32_16x16x32_bf16(g1[kt], f11h[kt], aA, 0, 0, 0);
            aB = __builtin_amdgcn_mfma_f32_16x16x32_bf16(g1[kt], f12h[kt], aB, 0, 0, 0);
            aC = __builtin_amdgcn_mfma_f32_16x16x32_bf16(g2[kt], f22h[kt], aC, 0, 0, 0);
            aA = __builtin_amdgcn_mfma_f32_16x16x32_bf16(g1[kt], f11l[kt], aA, 0, 0, 0);
            aB = __builtin_amdgcn_mfma_f32_16x16x32_bf16(g1[kt], f12l[kt], aB, 0, 0, 0);
            aC = __builtin_amdgcn_mfma_f32_16x16x32_bf16(g2[kt], f22l[kt], aC, 0, 0, 0);
        }
#pragma unroll
        for (int kk = 0; kk < 2; kk++)
            aO = __builtin_amdgcn_mfma_f32_16x16x32_bf16(g2[okp * 2 + kk], fO[kk], aO, 0, 0, 0);
        if (oval) {
#pragma unroll
            for (int r = 0; r < 4; r++) Opart[rb][w][q * 4 + r][li] = aO[r];
        }

        // ---- VALU segment ----
        if (w == 7 && i >= 2) {     // om(i-2) from Opart[wb] = WHO*S2(i-2)
#pragma unroll
            for (int ii = 0; ii < 5; ii++) {
                const int o = ob + ii;
                const int nt = o >> 4, lio = o & 15;
                const float s = (Opart[wb][nt][sm][lio] + Opart[wb][nt + 2][sm][lio])
                              + (Opart[wb][nt + 4][sm][lio] + Opart[wb][nt + 6][sm][lio]);
                om[ii] = fmaf(aoc[ii], om[ii], (1.f - aoc[ii]) * (bjoc[ii] + s));
            }
            if (i >= 13) {
                float e[5];
                float mx = om[0];
#pragma unroll
                for (int ii = 1; ii < 5; ii++) mx = fmaxf(mx, om[ii]);
                mx = fmaxf(mx, __shfl_xor(mx, 1));
                mx = fmaxf(mx, __shfl_xor(mx, 2));
                float se = 0.f;
#pragma unroll
                for (int ii = 0; ii < 5; ii++) { e[ii] = __expf(om[ii] - mx); se += e[ii]; }
                se += __shfl_xor(se, 1);
                se += __shfl_xor(se, 2);
                const float inv = 1.f / se;
#pragma unroll
                for (int ii = 0; ii < 5; ii++) accs[ii] += e[ii] * inv;
            }
        }
        // update-2(i): i2 = W12*S1(i) + W22*S2(i-1) + cc2 -> S2(i)
#pragma unroll
        for (int r = 0; r < 4; r++) {
            const bool sb = (s2bits >> r) & 1;
            const float i2 = aB[r] + aC[r] + cc2;
            b2a[r] = fmaf(r2c, b2a[r], sb ? omr2 : 0.f);
            const float B = fmaf(1.8f, b2a[r], 0.01f);
            h2m[r] = fmaf(a2, h2m[r], fmaf(oma2, i2, sb ? -B : 0.f));
            const bool sp = h2m[r] > B;
            s2bits = sp ? (s2bits | (1u << r)) : (s2bits & ~(1u << r));
            c2n[r] += sp ? 1.f : 0.f;
            sF2[wb][wbase + r * 8] = sp ? ONE : (unsigned short)0;
        }
        // update-1(i+1): i1 = xin(i+1) + W11*S1(i) -> S1(i+1)
#pragma unroll
        for (int r = 0; r < 4; r++) {
            const bool sb = (s1bits >> r) & 1;
            const float i1 = xt[r] + aA[r];
            b1a[r] = fmaf(r1c, b1a[r], sb ? omr1 : 0.f);
            const float B = fmaf(1.8f, b1a[r], 0.01f);
            h1m[r] = fmaf(a1, h1m[r], fmaf(oma1, i1, sb ? -B : 0.f));
            const bool sp = h1m[r] > B;
            s1bits = sp ? (s1bits | (1u << r)) : (s1bits & ~(1u << r));
            c1[r] += sp ? 1.f : 0.f;
            sF1[wb][wbase + r * 8] = sp ? ONE : (unsigned short)0;
        }
        __syncthreads();
    }

    // ================= epilogue =================
    // E1 (i=249): MFMAs on S1(249), S2(248); om(247); update-2(249)
    {
        const int rb = (TT - 1) & 1;   // = 1
        const int wb = rb ^ 1;
        const bf16x8* s1 = (const bf16x8*)sF1[rb];
        const bf16x8* s2 = (const bf16x8*)sF2[rb];
        bf16x8 g1[4], g2[4];
#pragma unroll
        for (int kt = 0; kt < 4; kt++) { g1[kt] = s1[kt * 64 + lane]; g2[kt] = s2[kt * 64 + lane]; }
        f32x4 aB = {0.f, 0.f, 0.f, 0.f}, aC = {0.f, 0.f, 0.f, 0.f}, aO = {0.f, 0.f, 0.f, 0.f};
#pragma unroll
        for (int kt = 0; kt < 4; kt++) {
            aB = __builtin_amdgcn_mfma_f32_16x16x32_bf16(g1[kt], f12h[kt], aB, 0, 0, 0);
            aC = __builtin_amdgcn_mfma_f32_16x16x32_bf16(g2[kt], f22h[kt], aC, 0, 0, 0);
            aB = __builtin_amdgcn_mfma_f32_16x16x32_bf16(g1[kt], f12l[kt], aB, 0, 0, 0);
            aC = __builtin_amdgcn_mfma_f32_16x16x32_bf16(g2[kt], f22l[kt], aC, 0, 0, 0);
        }
#pragma unroll
        for (int kk = 0; kk < 2; kk++)
            aO = __builtin_amdgcn_mfma_f32_16x16x32_bf16(g2[okp * 2 + kk], fO[kk], aO, 0, 0, 0);
        if (oval) {
#pragma unroll
            for (int r = 0; r < 4; r++) Opart[rb][w][q * 4 + r][li] = aO[r];
        }
        if (w == 7) {   // om(247) from Opart[wb=0]
#pragma unroll
            for (int ii = 0; ii < 5; ii++) {
                const int o = ob + ii;
                const int nt = o >> 4, lio = o & 15;
                const float s = (Opart[wb][nt][sm][lio] + Opart[wb][nt + 2][sm][lio])
                              + (Opart[wb][nt + 4][sm][lio] + Opart[wb][nt + 6][sm][lio]);
                om[ii] = fmaf(aoc[ii], om[ii], (1.f - aoc[ii]) * (bjoc[ii] + s));
            }
            float e[5];
            float mx = om[0];
#pragma unroll
            for (int ii = 1; ii < 5; ii++) mx = fmaxf(mx, om[ii]);
            mx = fmaxf(mx, __shfl_xor(mx, 1));
            mx = fmaxf(mx, __shfl_xor(mx, 2));
            float se = 0.f;
#pragma unroll
            for (int ii = 0; ii < 5; ii++) { e[ii] = __expf(om[ii] - mx); se += e[ii]; }
            se += __shfl_xor(se, 1);
            se += __shfl_xor(se, 2);
            const float inv = 1.f / se;
#pragma unroll
            for (int ii = 0; ii < 5; ii++) accs[ii] += e[ii] * inv;
        }
#pragma unroll
        for (int r = 0; r < 4; r++) {   // update-2(249)
            const bool sb = (s2bits >> r) & 1;
            const float i2 = aB[r] + aC[r] + cc2;
            b2a[r] = fmaf(r2c, b2a[r], sb ? omr2 : 0.f);
            const float B = fmaf(1.8f, b2a[r], 0.01f);
            h2m[r] = fmaf(a2, h2m[r], fmaf(oma2, i2, sb ? -B : 0.f));
            const bool sp = h2m[r] > B;
            c2n[r] += sp ? 1.f : 0.f;
            sF2[wb][wbase + r * 8] = sp ? ONE : (unsigned short)0;
        }
    }
    __syncthreads();
    // E2: WHO*S2(249) -> Opart[0]; om(248) from Opart[1]
    {
        const bf16x8* s2 = (const bf16x8*)sF2[0];
        bf16x8 g2[4];
#pragma unroll
        for (int kt = 0; kt < 4; kt++) g2[kt] = s2[kt * 64 + lane];
        f32x4 aO = {0.f, 0.f, 0.f, 0.f};
#pragma unroll
        for (int kk = 0; kk < 2; kk++)
            aO = __builtin_amdgcn_mfma_f32_16x16x32_bf16(g2[okp * 2 + kk], fO[kk], aO, 0, 0, 0);
        if (oval) {
#pragma unroll
            for (int r = 0; r < 4; r++) Opart[0][w][q * 4 + r][li] = aO[r];
        }
        if (w == 7) {
#pragma unroll
            for (int ii = 0; ii < 5; ii++) {
                const int o = ob + ii;
                const int nt = o >> 4, lio = o & 15;
                const float s = (Opart[1][nt][sm][lio] + Opart[1][nt + 2][sm][lio])
                              + (Opart[1][nt + 4][sm][lio] + Opart[1][nt + 6][sm][lio]);
                om[ii] = fmaf(aoc[ii], om[ii], (1.f - aoc[ii]) * (bjoc[ii] + s));
            }
            float e[5];
            float mx = om[0];
#pragma unroll
            for (int ii = 1; ii < 5; ii++) mx = fmaxf(mx, om[ii]);
            mx = fmaxf(mx, __shfl_xor(mx, 1));
            mx = fmaxf(mx, __shfl_xor(mx, 2));
            float se = 0.f;
#pragma unroll
            for (int ii = 0; ii < 5; ii++) { e[ii] = __expf(om[ii] - mx); se += e[ii]; }
            se += __shfl_xor(se, 1);
            se += __shfl_xor(se, 2);
            const float inv = 1.f / se;
#pragma unroll
            for (int ii = 0; ii < 5; ii++) accs[ii] += e[ii] * inv;
        }
    }
    __syncthreads();
    // E3: om(249) from Opart[0]; final softmax; store outputs
    if (w == 7) {
#pragma unroll
        for (int ii = 0; ii < 5; ii++) {
            const int o = ob + ii;
            const int nt = o >> 4, lio = o & 15;
            const float s = (Opart[0][nt][sm][lio] + Opart[0][nt + 2][sm][lio])
                          + (Opart[0][nt + 4][sm][lio] + Opart[0][nt + 6][sm][lio]);
            om[ii] = fmaf(aoc[ii], om[ii], (1.f - aoc[ii]) * (bjoc[ii] + s));
        }
        float e[5];
        float mx = om[0];
#pragma unroll
        for (int ii = 1; ii < 5; ii++) mx = fmaxf(mx, om[ii]);
        mx = fmaxf(mx, __shfl_xor(mx, 1));
        mx = fmaxf(mx, __shfl_xor(mx, 2));
        float se = 0.f;
#pragma unroll
        for (int ii = 0; ii < 5; ii++) { e[ii] = __expf(om[ii] - mx); se += e[ii]; }
        se += __shfl_xor(se, 1);
        se += __shfl_xor(se, 2);
        const float inv = 1.f / se;
#pragma unroll
        for (int ii = 0; ii < 5; ii++)
            out[(r0 + sm) * ON + ob + ii] = accs[ii] + e[ii] * inv;
    }
#pragma unroll
    for (int r = 0; r < 4; r++) {
        out[5120 + (r0 + q * 4 + r) * HN + col] = c1[r] * (1.f / 250.f);
        out[37888 + (r0 + q * 4 + r) * HN + col] = c2n[r] * (1.f / 250.f);
    }
}

// ---------------------------------------------------------------------------
extern "C" void kernel_launch(void* const* d_in, const int* in_sizes, int n_in,
                              void* d_out, int out_size, void* d_ws, size_t ws_size,
                              hipStream_t stream) {
    const float* x        = (const float*)d_in[0];
    const float* mask     = (const float*)d_in[1];
    const float* w_ih1    = (const float*)d_in[2];
    const float* b_ih1    = (const float*)d_in[3];
    const float* w_h1h1   = (const float*)d_in[4];
    const float* b_h1h1   = (const float*)d_in[5];
    const float* w_h1h2   = (const float*)d_in[6];
    const float* b_h1h2   = (const float*)d_in[7];
    const float* w_h2h2   = (const float*)d_in[8];
    const float* b_h2h2   = (const float*)d_in[9];
    const float* w_h2o    = (const float*)d_in[10];
    const float* b_h2o    = (const float*)d_in[11];
    const float* tau_adp1 = (const float*)d_in[12];
    const float* tau_adp2 = (const float*)d_in[13];
    const float* taum1    = (const float*)d_in[14];
    const float* taum2    = (const float*)d_in[15];
    const float* taumo    = (const float*)d_in[16];
    const float* h1m0     = (const float*)d_in[17];
    const float* h2m0     = (const float*)d_in[18];
    const float* om0      = (const float*)d_in[19];
    float* out = (float*)d_out;
    float* ws  = (float*)d_ws;

    float* xin = ws + XIN_OFF;
    unsigned short* wph = (unsigned short*)(ws + WPKH_OFF);
    unsigned short* wpl = (unsigned short*)(ws + WPKL_OFF);

    packw<<<352, 256, 0, stream>>>(w_ih1, wph, wpl);
    gemm_in<<<1000, 256, 0, stream>>>(x, (const bf16x8*)wph, (const bf16x8*)wpl,
                                      b_ih1, b_h1h1, xin);
    snn_scan<<<16, 512, 0, stream>>>(xin, mask, w_h1h1, w_h1h2, b_h1h2, w_h2h2,
                                     b_h2h2, w_h2o, b_h2o, tau_adp1, tau_adp2,
                                     taum1, taum2, taumo, h1m0, h2m0, om0, out);
}